// Round 14
// baseline (743.343 us; speedup 1.0000x reference)
//
#include <hip/hip_runtime.h>
#include <hip/hip_cooperative_groups.h>
#include <math.h>

namespace cg = cooperative_groups;

#define HH 512
#define WW 512
#define NTOT (64u*512u*512u)
#define NBLK 1024
#define TS 128
#define TROWS 132
#define TCH 18
#define TPIT 152        // LDS pitch (bf16); cols 144..151 are pad (stats scratch)
#define NTASK (TROWS*TCH)   // 2376
#define NITER 10

typedef __attribute__((ext_vector_type(8))) short short8;
typedef __attribute__((ext_vector_type(4))) float f32x4;

__device__ __forceinline__ float fsqrtf(float x) { return __builtin_amdgcn_sqrtf(x); }

__device__ __forceinline__ float shrinkf(float x, float l) {
    float a = x - l, b = x + l;
    return x + 0.5f * (fsqrtf(__builtin_fmaf(a, a, 1.f)) - fsqrtf(__builtin_fmaf(b, b, 1.f)));
}

__device__ __forceinline__ float bf2f(unsigned int u) {
    union { unsigned int i; float f; } cv; cv.i = u << 16; return cv.f;
}
__device__ __forceinline__ float lo2f(unsigned int p) {
    union { unsigned int i; float f; } cv; cv.i = p << 16; return cv.f;
}
__device__ __forceinline__ float hi2f(unsigned int p) {
    union { unsigned int i; float f; } cv; cv.i = p & 0xffff0000u; return cv.f;
}

__device__ __forceinline__ unsigned int cvtpk(float lo, float hi) {
    unsigned int r;
    asm("v_cvt_pk_bf16_f32 %0, %1, %2" : "=v"(r) : "v"(lo), "v"(hi));
    return r;
}

__device__ __forceinline__ void bf8(uint4 u, float* f) {
    f[0] = bf2f(u.x & 0xffffu); f[1] = bf2f(u.x >> 16);
    f[2] = bf2f(u.y & 0xffffu); f[3] = bf2f(u.y >> 16);
    f[4] = bf2f(u.z & 0xffffu); f[5] = bf2f(u.z >> 16);
    f[6] = bf2f(u.w & 0xffffu); f[7] = bf2f(u.w >> 16);
}

// ===================== persistent cooperative mega-kernel =====================
__global__ __launch_bounds__(256, 4) void mega_k(
    const float* __restrict__ yin,
    unsigned short* __restrict__ t1,
    unsigned short* __restrict__ t2,
    float* __restrict__ outf32,
    const float* __restrict__ wgt,
    const float* __restrict__ bias,
    const float* __restrict__ gamma,
    const float* __restrict__ beta,
    const float* __restrict__ lambd,
    float* __restrict__ p1,
    float* __restrict__ p2,
    float* __restrict__ p3)
{
    __shared__ unsigned short tile[TROWS * TPIT];   // 40,128 B
    cg::grid_group gg = cg::this_grid();

    const int tid = threadIdx.x;
    const int bid = blockIdx.x;
    const int img = bid >> 4;
    const int rem = bid & 15;
    const int by = ((rem >> 2) & 3) * TS;
    const int bx = (rem & 3) * TS;
    const size_t ibase = (size_t)img * (HH * WW);

    const int lane = tid & 63;
    const int lm = lane & 15;
    const int kb = lane >> 4;
    const int wv = tid >> 6;
    const uint4 z4 = make_uint4(0u,0u,0u,0u);

    // uniform weights -> SGPRs; lane-local B fragments
    float wloc[25];
#pragma unroll
    for (int i = 0; i < 25; i++) wloc[i] = wgt[i];
    const int basei = kb * 8 - lm - 6;
    short8 bfr[5];
#pragma unroll
    for (int ky = 0; ky < 5; ky++) {
        unsigned pkw[4];
#pragma unroll
        for (int jj = 0; jj < 4; jj++) {
            float v0 = 0.f, v1 = 0.f;
            const int i0 = basei + 2 * jj, i1 = i0 + 1;
#pragma unroll
            for (int t = 0; t < 5; t++) {
                if (i0 == t) v0 = wloc[ky * 5 + t];
                if (i1 == t) v1 = wloc[ky * 5 + t];
            }
            pkw[jj] = cvtpk(v0, v1);
        }
        union { unsigned u[4]; short8 s; } cv;
        cv.u[0]=pkw[0]; cv.u[1]=pkw[1]; cv.u[2]=pkw[2]; cv.u[3]=pkw[3];
        bfr[ky] = cv.s;
    }
    const float b0 = bias[0];
    const float gam = gamma[0], bet = beta[0];

    // chunk geometry helper
    auto chunkOK = [&](int task, int& row, int& ch, size_t& g) -> bool {
        row = task / TCH; ch = task - row * TCH;
        const int gy = by + row - 2, gx0 = bx + ch * 8 - 8;
        g = ibase + (size_t)gy * WW + gx0;
        return gy >= 0 && gy < HH && gx0 >= 0 && gx0 <= WW - 8;
    };

    // cross-block stats: butterfly + pad-column scratch (cols 144.. of rows 0..3)
    auto stats2 = [&](const float* part, float& scl, float& shf) {
        double sd = 0.0, qd = 0.0;
#pragma unroll
        for (int k = 0; k < 4; k++) {
            const int i = tid + k * 256;
            sd += (double)part[2 * i]; qd += (double)part[2 * i + 1];
        }
#pragma unroll
        for (int off = 32; off > 0; off >>= 1) {
            sd += __shfl_xor(sd, off); qd += __shfl_xor(qd, off);
        }
        if (lane == 0) {
            double* sc = (double*)&tile[wv * TPIT + 144];
            sc[0] = sd; sc[1] = qd;
        }
        __syncthreads();
        double S = 0.0, Q = 0.0;
#pragma unroll
        for (int w = 0; w < 4; w++) {
            const double* sc = (const double*)&tile[w * TPIT + 144];
            S += sc[0]; Q += sc[1];
        }
        const double mean = S / (double)NTOT;
        const double var  = Q / (double)NTOT - mean * mean;
        const double scd  = (double)gam / sqrt(var + 1e-5);
        scl = (float)scd;
        shf = (float)((double)bet - mean * scd);
        __syncthreads();
    };

    // load halo strips of src into tile halo slots (328 chunk tasks)
    auto halo_load = [&](const unsigned short* src) {
        for (int t = tid; t < 328; t += 256) {
            int r, ch;
            if (t < 72) { const int rr = t / 18; r = (rr < 2) ? rr : 128 + rr; ch = t - rr * 18; }
            else        { const int s2_ = t - 72; r = 2 + (s2_ >> 1); ch = (s2_ & 1) ? 17 : 0; }
            const int gy = by + r - 2, gx0 = bx + ch * 8 - 8;
            uint4 v = z4;
            if (gy >= 0 && gy < HH && gx0 >= 0 && gx0 <= WW - 8)
                v = *(const uint4*)(src + ibase + (size_t)gy * WW + gx0);
            *(uint4*)&tile[r * TPIT + ch * 8] = v;
        }
    };

    // MFMA conv over staged tile + epilogue (global write optional) + partials
    // + write acc (bf16) into tile interior + fence + grid sync
    auto conv_phase = [&](unsigned short* gdst, float* pdst) {
        __syncthreads();
        const int r0w = wv * 32;
        f32x4 acc[2][8];
#pragma unroll
        for (int st = 0; st < 2; st++)
#pragma unroll
            for (int ct = 0; ct < 8; ct++)
                acc[st][ct] = (f32x4){0.f,0.f,0.f,0.f};
#pragma unroll
        for (int ky = 0; ky < 5; ky++) {
            const short8 b = bfr[ky];
#pragma unroll
            for (int st = 0; st < 2; st++) {
                const unsigned short* ab = &tile[(r0w + st*16 + lm + ky) * TPIT + kb * 8];
#pragma unroll
                for (int ct = 0; ct < 8; ct++) {
                    short8 a = *(const short8*)(ab + ct * 16);
                    acc[st][ct] = __builtin_amdgcn_mfma_f32_16x16x32_bf16(a, b, acc[st][ct], 0, 0, 0);
                }
            }
        }
        float s = 0.f, q = 0.f;
#pragma unroll
        for (int st = 0; st < 2; st++)
#pragma unroll
            for (int ct = 0; ct < 8; ct++) {
                const f32x4 a = acc[st][ct];
                const unsigned p01 = cvtpk(a[0] + b0, a[1] + b0);
                const unsigned p23 = cvtpk(a[2] + b0, a[3] + b0);
                if (gdst) {
                    const int grow0 = by + r0w + st * 16 + kb * 4;
                    const size_t gb = ibase + (size_t)grow0 * WW + bx + ct * 16 + lm;
                    gdst[gb]          = (unsigned short)(p01 & 0xffffu);
                    gdst[gb + WW]     = (unsigned short)(p01 >> 16);
                    gdst[gb + 2*WW]   = (unsigned short)(p23 & 0xffffu);
                    gdst[gb + 3*WW]   = (unsigned short)(p23 >> 16);
                }
                const float fr0 = lo2f(p01), fr1 = hi2f(p01), fr2 = lo2f(p23), fr3 = hi2f(p23);
                s += fr0 + fr1 + fr2 + fr3;
                q = __builtin_fmaf(fr0, fr0, __builtin_fmaf(fr1, fr1,
                    __builtin_fmaf(fr2, fr2, __builtin_fmaf(fr3, fr3, q))));
            }
        __syncthreads();
        float* red = (float*)tile;
        red[tid] = s; red[256 + tid] = q;
        __syncthreads();
        for (int off = 128; off > 0; off >>= 1) {
            if (tid < off) { red[tid] += red[tid+off]; red[256+tid] += red[256+tid+off]; }
            __syncthreads();
        }
        if (tid == 0) { pdst[bid * 2] = red[0]; pdst[bid * 2 + 1] = red[256]; }
        __syncthreads();
        // retain output in tile interior (bf16, identical bits to gdst)
#pragma unroll
        for (int st = 0; st < 2; st++)
#pragma unroll
            for (int ct = 0; ct < 8; ct++) {
                const f32x4 a = acc[st][ct];
                const unsigned p01 = cvtpk(a[0] + b0, a[1] + b0);
                const unsigned p23 = cvtpk(a[2] + b0, a[3] + b0);
                const int tr = r0w + st * 16 + kb * 4 + 2;
                const int c  = 8 + ct * 16 + lm;
                tile[(tr + 0) * TPIT + c] = (unsigned short)(p01 & 0xffffu);
                tile[(tr + 1) * TPIT + c] = (unsigned short)(p01 >> 16);
                tile[(tr + 2) * TPIT + c] = (unsigned short)(p23 & 0xffffu);
                tile[(tr + 3) * TPIT + c] = (unsigned short)(p23 >> 16);
            }
        __threadfence();
        gg.sync();
    };

    // =================== PHASE A: y -> conv -> t1 ===================
    {
        uint4 sA0,sB0,sA1,sB1,sA2,sB2;
        auto loadY = [&](int task, uint4& A, uint4& B) {
            A = z4; B = z4;
            int row, ch; size_t g;
            if (task < NTASK && chunkOK(task, row, ch, g)) {
                A = *(const uint4*)(yin + g);
                B = *(const uint4*)(yin + g + 4);
            }
        };
        loadY(tid, sA0, sB0); loadY(tid+256, sA1, sB1); loadY(tid+512, sA2, sB2);
#pragma unroll
        for (int t = 0; t < NITER; t++) {
            const int task = tid + t * 256;
            if (task < NTASK) {
                int row, ch; size_t g;
                const bool ok = chunkOK(task, row, ch, g);
                uint4 pk = z4;
                if (ok) {
                    const float4 a = *(const float4*)&sA0;
                    const float4 b = *(const float4*)&sB0;
                    pk.x = cvtpk(a.x, a.y); pk.y = cvtpk(a.z, a.w);
                    pk.z = cvtpk(b.x, b.y); pk.w = cvtpk(b.z, b.w);
                }
                *(uint4*)&tile[row * TPIT + ch * 8] = pk;
            }
            sA0=sA1; sB0=sB1; sA1=sA2; sB1=sB2;
            if (t + 3 < NITER) loadY(tid + (t+3)*256, sA2, sB2);
            else { sA2 = z4; sB2 = z4; }
        }
    }
    conv_phase(t1, p1);

    // =================== PHASE B: shrink(n1(t1),l0) -> conv -> t2 ===================
    float s1, h1;
    stats2(p1, s1, h1);
    {
        const float l0 = lambd[0];
        halo_load(t1);
        __syncthreads();
#pragma unroll
        for (int t = 0; t < NITER; t++) {
            const int task = tid + t * 256;
            if (task < NTASK) {
                int row, ch; size_t g;
                const bool ok = chunkOK(task, row, ch, g);
                unsigned short* tp = &tile[row * TPIT + ch * 8];
                uint4 pk = z4;
                if (ok) {
                    uint4 u1 = *(const uint4*)tp;
                    float f1[8]; bf8(u1, f1);
                    float v[8];
#pragma unroll
                    for (int k = 0; k < 8; k++)
                        v[k] = shrinkf(__builtin_fmaf(f1[k], s1, h1), l0);
                    pk.x = cvtpk(v[0], v[1]); pk.y = cvtpk(v[2], v[3]);
                    pk.z = cvtpk(v[4], v[5]); pk.w = cvtpk(v[6], v[7]);
                }
                *(uint4*)tp = pk;
            }
        }
    }
    conv_phase(t2, p2);

    // =========== PHASE C: shrink(n2(t2)+n1(t1),l1) -> conv -> t3 (LDS only) ===========
    {
        float s2v, h2;
        stats2(p2, s2v, h2);
        const float l1 = lambd[1];
        halo_load(t2);
        auto loadT1 = [&](int task, uint4& A) {
            A = z4;
            int row, ch; size_t g;
            if (task < NTASK && chunkOK(task, row, ch, g))
                A = *(const uint4*)(t1 + g);
        };
        uint4 a0, a1, a2;
        loadT1(tid, a0); loadT1(tid+256, a1); loadT1(tid+512, a2);
        __syncthreads();
#pragma unroll
        for (int t = 0; t < NITER; t++) {
            const int task = tid + t * 256;
            if (task < NTASK) {
                int row, ch; size_t g;
                const bool ok = chunkOK(task, row, ch, g);
                unsigned short* tp = &tile[row * TPIT + ch * 8];
                uint4 pk = z4;
                if (ok) {
                    uint4 u2 = *(const uint4*)tp;
                    float f1[8], f2[8]; bf8(a0, f1); bf8(u2, f2);
                    float v[8];
#pragma unroll
                    for (int k = 0; k < 8; k++) {
                        float x = __builtin_fmaf(f2[k], s2v, h2)
                                + __builtin_fmaf(f1[k], s1, h1);
                        v[k] = shrinkf(x, l1);
                    }
                    pk.x = cvtpk(v[0], v[1]); pk.y = cvtpk(v[2], v[3]);
                    pk.z = cvtpk(v[4], v[5]); pk.w = cvtpk(v[6], v[7]);
                }
                *(uint4*)tp = pk;
            }
            a0 = a1; a1 = a2;
            if (t + 3 < NITER) loadT1(tid + (t+3)*256, a2);
            else a2 = z4;
        }
    }
    conv_phase(nullptr, p3);

    // =================== PHASE D: out = shrink(n3(t3)+n1(t1), l2) ===================
    {
        float s3, h3;
        stats2(p3, s3, h3);
        const float l2v = lambd[2];
        // 8 chunks/thread over interior; t3 from LDS, t1 from global (L3-hot)
        size_t gaddr[1];  // silence unused warning pattern; use named regs below
        (void)gaddr;
        uint4 u0,u1v,u2v,u3v,u4v,u5v,u6v,u7v;
        int rw, c8;
        #define GADDR(t, taskv) \
            rw = (taskv) >> 4; c8 = (taskv) & 15;
        {
            int task;
            task = tid;            GADDR(0, task); u0  = *(const uint4*)(t1 + ibase + (size_t)(by+rw)*WW + bx + c8*8);
            task = tid + 256;      GADDR(1, task); u1v = *(const uint4*)(t1 + ibase + (size_t)(by+rw)*WW + bx + c8*8);
            task = tid + 512;      GADDR(2, task); u2v = *(const uint4*)(t1 + ibase + (size_t)(by+rw)*WW + bx + c8*8);
            task = tid + 768;      GADDR(3, task); u3v = *(const uint4*)(t1 + ibase + (size_t)(by+rw)*WW + bx + c8*8);
            task = tid + 1024;     GADDR(4, task); u4v = *(const uint4*)(t1 + ibase + (size_t)(by+rw)*WW + bx + c8*8);
            task = tid + 1280;     GADDR(5, task); u5v = *(const uint4*)(t1 + ibase + (size_t)(by+rw)*WW + bx + c8*8);
            task = tid + 1536;     GADDR(6, task); u6v = *(const uint4*)(t1 + ibase + (size_t)(by+rw)*WW + bx + c8*8);
            task = tid + 1792;     GADDR(7, task); u7v = *(const uint4*)(t1 + ibase + (size_t)(by+rw)*WW + bx + c8*8);
        }
        #undef GADDR
        auto emitD = [&](int task, uint4 ut1) {
            const int row = task >> 4;
            const int cc  = task & 15;
            const size_t g = ibase + (size_t)(by + row) * WW + bx + cc * 8;
            uint4 v3 = *(const uint4*)&tile[(row + 2) * TPIT + 8 + cc * 8];
            float f1[8], f3[8]; bf8(ut1, f1); bf8(v3, f3);
            float r[8];
#pragma unroll
            for (int k = 0; k < 8; k++) {
                float v = __builtin_fmaf(f3[k], s3, h3) + __builtin_fmaf(f1[k], s1, h1);
                r[k] = shrinkf(v, l2v);
            }
            *(float4*)(outf32 + g)     = make_float4(r[0], r[1], r[2], r[3]);
            *(float4*)(outf32 + g + 4) = make_float4(r[4], r[5], r[6], r[7]);
        };
        emitD(tid,        u0);  emitD(tid + 256,  u1v);
        emitD(tid + 512,  u2v); emitD(tid + 768,  u3v);
        emitD(tid + 1024, u4v); emitD(tid + 1280, u5v);
        emitD(tid + 1536, u6v); emitD(tid + 1792, u7v);
    }
}

// ===================== round-13 fallback kernels (proven) =====================
__device__ __forceinline__ void stats_reduce(
    const float* __restrict__ part, double* rs, double* rq, int tid,
    float gam, float bet, float& scl_out, float& shf_out)
{
    double sd = 0.0, qd = 0.0;
#pragma unroll
    for (int k = 0; k < 4; k++) {
        const int i = tid + k * 256;
        sd += (double)part[2 * i];
        qd += (double)part[2 * i + 1];
    }
    rs[tid] = sd; rq[tid] = qd;
    __syncthreads();
    for (int off = 128; off > 0; off >>= 1) {
        if (tid < off) { rs[tid] += rs[tid + off]; rq[tid] += rq[tid + off]; }
        __syncthreads();
    }
    const double mean = rs[0] / (double)NTOT;
    const double var  = rq[0] / (double)NTOT - mean * mean;
    const double scl  = (double)gam / sqrt(var + 1e-5);
    scl_out = (float)scl;
    shf_out = (float)((double)bet - mean * scl);
    __syncthreads();
}

template <int MODE, bool OBF>
__global__ __launch_bounds__(256, 4) void conv_k(
    const float* __restrict__ yin,
    const unsigned short* __restrict__ t1,
    const unsigned short* __restrict__ t2,
    unsigned short* __restrict__ outbf,
    float* __restrict__ outf32,
    const float* __restrict__ wgt,
    const float* __restrict__ bias,
    const float* __restrict__ prevPart,
    const float* __restrict__ statsIn,
    float* __restrict__ statsOut,
    const float* __restrict__ gamma,
    const float* __restrict__ beta,
    const float* __restrict__ lambd,
    float* __restrict__ partials)
{
    __shared__ unsigned short tile[TROWS * TPIT];

    const int tid = threadIdx.x;
    const int by = blockIdx.y * TS;
    const int bx = blockIdx.x * TS;
    const size_t ibase = (size_t)blockIdx.z * (HH * WW);

    float wloc[25];
#pragma unroll
    for (int i = 0; i < 25; i++) wloc[i] = wgt[i];

    const int lane = tid & 63;
    const int lm = lane & 15;
    const int kb = lane >> 4;
    const int basei = kb * 8 - lm - 6;
    short8 bfr[5];
#pragma unroll
    for (int ky = 0; ky < 5; ky++) {
        unsigned pkw[4];
#pragma unroll
        for (int jj = 0; jj < 4; jj++) {
            float v0 = 0.f, v1 = 0.f;
            const int i0 = basei + 2 * jj, i1 = i0 + 1;
#pragma unroll
            for (int t = 0; t < 5; t++) {
                if (i0 == t) v0 = wloc[ky * 5 + t];
                if (i1 == t) v1 = wloc[ky * 5 + t];
            }
            pkw[jj] = cvtpk(v0, v1);
        }
        union { unsigned u[4]; short8 s; } cv;
        cv.u[0]=pkw[0]; cv.u[1]=pkw[1]; cv.u[2]=pkw[2]; cv.u[3]=pkw[3];
        bfr[ky] = cv.s;
    }

    auto loadT = [&](int task, uint4& A, uint4& B) {
        A = make_uint4(0u,0u,0u,0u); B = make_uint4(0u,0u,0u,0u);
        const int row = task / TCH;
        const int ch  = task - row * TCH;
        const int gy  = by + row - 2;
        const int gx0 = bx + ch * 8 - 8;
        if (task < NTASK && gy >= 0 && gy < HH && gx0 >= 0 && gx0 <= WW - 8) {
            const size_t g = ibase + (size_t)gy * WW + gx0;
            if constexpr (MODE == 0) {
                A = *(const uint4*)(yin + g);
                B = *(const uint4*)(yin + g + 4);
            } else if constexpr (MODE == 1) {
                A = *(const uint4*)(t1 + g);
            } else {
                A = *(const uint4*)(t1 + g);
                B = *(const uint4*)(t2 + g);
            }
        }
    };

    uint4 sA0, sB0, sA1, sB1, sA2, sB2;
    loadT(tid,        sA0, sB0);
    loadT(tid + 256,  sA1, sB1);
    loadT(tid + 512,  sA2, sB2);

    float s1 = 0.f, h1 = 0.f, s2v = 0.f, h2 = 0.f, lam = 0.f;
    if constexpr (MODE == 1) {
        stats_reduce(prevPart, (double*)tile, ((double*)tile) + 256, tid,
                     gamma[0], beta[0], s1, h1);
        lam = lambd[0];
        if (tid == 0 && blockIdx.x == 0 && blockIdx.y == 0 && blockIdx.z == 0) {
            statsOut[0] = s1; statsOut[1] = h1;
        }
    }
    if constexpr (MODE == 2) {
        stats_reduce(prevPart, (double*)tile, ((double*)tile) + 256, tid,
                     gamma[0], beta[0], s2v, h2);
        s1 = statsIn[0]; h1 = statsIn[1];
        lam = lambd[1];
    }

    auto procT = [&](int task, uint4 A, uint4 B) {
        const int row = task / TCH;
        const int ch  = task - row * TCH;
        uint4 pk = make_uint4(0u,0u,0u,0u);
        if constexpr (MODE == 0) {
            const float4 a = *(const float4*)&A;
            const float4 b = *(const float4*)&B;
            pk.x = cvtpk(a.x, a.y); pk.y = cvtpk(a.z, a.w);
            pk.z = cvtpk(b.x, b.y); pk.w = cvtpk(b.z, b.w);
        } else if constexpr (MODE == 1) {
            float f1[8]; bf8(A, f1);
            float v[8];
#pragma unroll
            for (int k = 0; k < 8; k++)
                v[k] = shrinkf(__builtin_fmaf(f1[k], s1, h1), lam);
            pk.x = cvtpk(v[0], v[1]); pk.y = cvtpk(v[2], v[3]);
            pk.z = cvtpk(v[4], v[5]); pk.w = cvtpk(v[6], v[7]);
        } else {
            float f1[8], f2[8]; bf8(A, f1); bf8(B, f2);
            float v[8];
#pragma unroll
            for (int k = 0; k < 8; k++) {
                float x = __builtin_fmaf(f2[k], s2v, h2)
                        + __builtin_fmaf(f1[k], s1, h1);
                v[k] = shrinkf(x, lam);
            }
            pk.x = cvtpk(v[0], v[1]); pk.y = cvtpk(v[2], v[3]);
            pk.z = cvtpk(v[4], v[5]); pk.w = cvtpk(v[6], v[7]);
        }
        const int gy  = by + row - 2;
        const int gx0 = bx + ch * 8 - 8;
        if (!(gy >= 0 && gy < HH && gx0 >= 0 && gx0 <= WW - 8))
            pk = make_uint4(0u,0u,0u,0u);
        *(uint4*)&tile[row * TPIT + ch * 8] = pk;
    };

#pragma unroll
    for (int t = 0; t < NITER; t++) {
        const int task = tid + t * 256;
        if (task < NTASK) procT(task, sA0, sB0);
        sA0 = sA1; sB0 = sB1;
        sA1 = sA2; sB1 = sB2;
        if (t + 3 < NITER) loadT(tid + (t + 3) * 256, sA2, sB2);
        else { sA2 = make_uint4(0u,0u,0u,0u); sB2 = make_uint4(0u,0u,0u,0u); }
    }

    const float b0 = bias[0];
    __syncthreads();

    const int wv = tid >> 6;
    const int r0w = wv * 32;

    f32x4 acc[2][8];
#pragma unroll
    for (int st = 0; st < 2; st++)
#pragma unroll
        for (int ct = 0; ct < 8; ct++)
            acc[st][ct] = (f32x4){0.f, 0.f, 0.f, 0.f};

#pragma unroll
    for (int ky = 0; ky < 5; ky++) {
        const short8 b = bfr[ky];
#pragma unroll
        for (int st = 0; st < 2; st++) {
            const unsigned short* ab = &tile[(r0w + st * 16 + lm + ky) * TPIT + kb * 8];
#pragma unroll
            for (int ct = 0; ct < 8; ct++) {
                short8 a = *(const short8*)(ab + ct * 16);
                acc[st][ct] = __builtin_amdgcn_mfma_f32_16x16x32_bf16(a, b, acc[st][ct], 0, 0, 0);
            }
        }
    }

    float s = 0.f, q = 0.f;
#pragma unroll
    for (int st = 0; st < 2; st++) {
#pragma unroll
        for (int ct = 0; ct < 8; ct++) {
            const f32x4 a = acc[st][ct];
            const int grow0 = by + r0w + st * 16 + kb * 4;
            const size_t base = ibase + (size_t)grow0 * WW + bx + ct * 16 + lm;
            if constexpr (OBF) {
                unsigned p01 = cvtpk(a[0] + b0, a[1] + b0);
                unsigned p23 = cvtpk(a[2] + b0, a[3] + b0);
                outbf[base]          = (unsigned short)(p01 & 0xffffu);
                outbf[base + WW]     = (unsigned short)(p01 >> 16);
                outbf[base + 2 * WW] = (unsigned short)(p23 & 0xffffu);
                outbf[base + 3 * WW] = (unsigned short)(p23 >> 16);
                float fr0 = lo2f(p01), fr1 = hi2f(p01), fr2 = lo2f(p23), fr3 = hi2f(p23);
                s += fr0 + fr1 + fr2 + fr3;
                q = __builtin_fmaf(fr0, fr0, __builtin_fmaf(fr1, fr1,
                    __builtin_fmaf(fr2, fr2, __builtin_fmaf(fr3, fr3, q))));
            } else {
                float f0 = a[0] + b0, f1v = a[1] + b0, f2v = a[2] + b0, f3v = a[3] + b0;
                outf32[base]          = f0;
                outf32[base + WW]     = f1v;
                outf32[base + 2 * WW] = f2v;
                outf32[base + 3 * WW] = f3v;
                s += f0 + f1v + f2v + f3v;
                q = __builtin_fmaf(f0, f0, __builtin_fmaf(f1v, f1v,
                    __builtin_fmaf(f2v, f2v, __builtin_fmaf(f3v, f3v, q))));
            }
        }
    }

    __syncthreads();
    float* red = (float*)tile;
    red[tid] = s; red[256 + tid] = q;
    __syncthreads();
    for (int off = 128; off > 0; off >>= 1) {
        if (tid < off) { red[tid] += red[tid + off]; red[256 + tid] += red[256 + tid + off]; }
        __syncthreads();
    }
    if (tid == 0) {
        const int bid = (blockIdx.z * 4 + blockIdx.y) * 4 + blockIdx.x;
        partials[bid * 2] = red[0];
        partials[bid * 2 + 1] = red[256];
    }
}

template <bool T3BF>
__global__ __launch_bounds__(256) void final_k(
    const unsigned short* __restrict__ t1,
    const unsigned short* __restrict__ t3b,
    float* __restrict__ io,
    const float* __restrict__ p3,
    const float* __restrict__ statsIn,
    const float* __restrict__ gamma,
    const float* __restrict__ beta,
    const float* __restrict__ lambd)
{
    __shared__ double rbuf[512];
    const int tid = threadIdx.x;

    float s3, h3;
    stats_reduce(p3, rbuf, rbuf + 256, tid, gamma[0], beta[0], s3, h3);
    const float s1 = statsIn[0], h1 = statsIn[1];
    const float lam = lambd[2];

#pragma unroll
    for (int c = 0; c < 8; c++) {
        const size_t idx = ((size_t)c * 1024 + blockIdx.x) * 256 + tid;
        const size_t base = idx * 8;

        uint4 u1 = *(const uint4*)(t1 + base);
        float f1[8]; bf8(u1, f1);

        float t3v[8];
        if constexpr (T3BF) {
            uint4 u3 = *(const uint4*)(t3b + base);
            bf8(u3, t3v);
        } else {
            float4 a0 = *(const float4*)(io + base);
            float4 a1 = *(const float4*)(io + base + 4);
            t3v[0]=a0.x; t3v[1]=a0.y; t3v[2]=a0.z; t3v[3]=a0.w;
            t3v[4]=a1.x; t3v[5]=a1.y; t3v[6]=a1.z; t3v[7]=a1.w;
        }

        float r[8];
#pragma unroll
        for (int k = 0; k < 8; k++) {
            float v = __builtin_fmaf(t3v[k], s3, h3) + __builtin_fmaf(f1[k], s1, h1);
            r[k] = shrinkf(v, lam);
        }
        *(float4*)(io + base)     = make_float4(r[0], r[1], r[2], r[3]);
        *(float4*)(io + base + 4) = make_float4(r[4], r[5], r[6], r[7]);
    }
}

// ================================ launcher ==================================
extern "C" void kernel_launch(void* const* d_in, const int* in_sizes, int n_in,
                              void* d_out, int out_size, void* d_ws, size_t ws_size,
                              hipStream_t stream)
{
    const float* y     = (const float*)d_in[0];
    const float* wgt   = (const float*)d_in[1];
    const float* bias  = (const float*)d_in[2];
    const float* gamma = (const float*)d_in[3];
    const float* beta  = (const float*)d_in[4];
    const float* lambd = (const float*)d_in[5];
    float* out = (float*)d_out;

    char* ws = (char*)d_ws;
    unsigned short* t1 = (unsigned short*)ws;                    // 33,554,432 B
    unsigned short* t2 = (unsigned short*)(ws + 33554432ull);    // 33,554,432 B

    // mega path scratch (right after t2)
    float* mp1 = (float*)(ws + 67108864ull);
    float* mp2 = (float*)(ws + 67108864ull + 8192ull);
    float* mp3 = (float*)(ws + 67108864ull + 16384ull);

    bool coop_done = false;
    if (ws_size >= 67133448ull) {
        void* args[12] = {
            (void*)&y, (void*)&t1, (void*)&t2, (void*)&out,
            (void*)&wgt, (void*)&bias, (void*)&gamma, (void*)&beta,
            (void*)&lambd, (void*)&mp1, (void*)&mp2, (void*)&mp3
        };
        hipError_t e = hipLaunchCooperativeKernel(
            reinterpret_cast<const void*>(&mega_k),
            dim3(NBLK, 1, 1), dim3(256, 1, 1), args, 0, stream);
        if (e == hipSuccess) coop_done = true;
        else (void)hipGetLastError();   // clear sticky error, fall back
    }
    if (coop_done) return;

    // -------- fallback: proven round-13 four-kernel path --------
    unsigned short* t3 = (unsigned short*)(ws + 67108864ull);
    const bool t3bf = (ws_size >= 100696088ull);
    const size_t poff = t3bf ? 100663296ull : 67108864ull;
    float* p1    = (float*)(ws + poff);
    float* p2    = (float*)(ws + poff + 8192ull);
    float* p3    = (float*)(ws + poff + 16384ull);
    float* stats = (float*)(ws + poff + 24576ull);

    dim3 grid(4, 4, 64), blk(256);
    conv_k<0, true><<<grid, blk, 0, stream>>>(y, nullptr, nullptr, t1, nullptr,
                                              wgt, bias, nullptr, nullptr, nullptr,
                                              gamma, beta, lambd, p1);
    conv_k<1, true><<<grid, blk, 0, stream>>>(nullptr, t1, nullptr, t2, nullptr,
                                              wgt, bias, p1, nullptr, stats,
                                              gamma, beta, lambd, p2);
    if (t3bf) {
        conv_k<2, true><<<grid, blk, 0, stream>>>(nullptr, t1, t2, t3, nullptr,
                                                  wgt, bias, p2, stats, nullptr,
                                                  gamma, beta, lambd, p3);
        final_k<true><<<1024, blk, 0, stream>>>(t1, t3, out, p3, stats,
                                                gamma, beta, lambd);
    } else {
        conv_k<2, false><<<grid, blk, 0, stream>>>(nullptr, t1, t2, nullptr, out,
                                                   wgt, bias, p2, stats, nullptr,
                                                   gamma, beta, lambd, p3);
        final_k<false><<<1024, blk, 0, stream>>>(t1, nullptr, out, p3, stats,
                                                 gamma, beta, lambd);
    }
}

// Round 15
// 91.331 us; speedup vs baseline: 8.1390x; 8.1390x over previous
//
#include <hip/hip_runtime.h>
#include <math.h>

#define HH 512
#define WW 512
#define NTOT (64u*512u*512u)
#define TS 128
#define TROWS 132
#define TCH 18
#define TPIT 152        // LDS pitch (bf16): 304 B/row, 16B-aligned
#define NTASK (TROWS*TCH)   // 2376
#define NITER 10
#define NPART 4096          // per-wave partial pairs (1024 blocks x 4 waves)

typedef __attribute__((ext_vector_type(8))) short short8;
typedef __attribute__((ext_vector_type(4))) float f32x4;

__device__ __forceinline__ float fsqrtf(float x) { return __builtin_amdgcn_sqrtf(x); }

__device__ __forceinline__ float shrinkf(float x, float l) {
    float a = x - l, b = x + l;
    return x + 0.5f * (fsqrtf(__builtin_fmaf(a, a, 1.f)) - fsqrtf(__builtin_fmaf(b, b, 1.f)));
}

__device__ __forceinline__ float bf2f(unsigned int u) {
    union { unsigned int i; float f; } cv; cv.i = u << 16; return cv.f;
}
__device__ __forceinline__ float lo2f(unsigned int p) {
    union { unsigned int i; float f; } cv; cv.i = p << 16; return cv.f;
}
__device__ __forceinline__ float hi2f(unsigned int p) {
    union { unsigned int i; float f; } cv; cv.i = p & 0xffff0000u; return cv.f;
}

// v_cvt_pk_bf16_f32 (RNE): dst = bf16(lo) | (bf16(hi) << 16)
__device__ __forceinline__ unsigned int cvtpk(float lo, float hi) {
    unsigned int r;
    asm("v_cvt_pk_bf16_f32 %0, %1, %2" : "=v"(r) : "v"(lo), "v"(hi));
    return r;
}

__device__ __forceinline__ void bf8(uint4 u, float* f) {
    f[0] = bf2f(u.x & 0xffffu); f[1] = bf2f(u.x >> 16);
    f[2] = bf2f(u.y & 0xffffu); f[3] = bf2f(u.y >> 16);
    f[4] = bf2f(u.z & 0xffffu); f[5] = bf2f(u.z >> 16);
    f[6] = bf2f(u.w & 0xffffu); f[7] = bf2f(u.w >> 16);
}

// Fast stats reduce over NPART per-wave partial pairs: 16 pairs/thread (f64)
// -> wave butterfly -> 4 LDS slots -> ONE barrier -> combine. Deterministic.
__device__ __forceinline__ void stats_fast(
    const float* __restrict__ part, double* __restrict__ sbuf,
    int tid, int lane, int wv,
    float gam, float bet, float& scl_out, float& shf_out)
{
    double sd = 0.0, qd = 0.0;
#pragma unroll
    for (int k = 0; k < 16; k++) {
        const int i = tid + k * 256;
        sd += (double)part[2 * i];
        qd += (double)part[2 * i + 1];
    }
#pragma unroll
    for (int off = 32; off > 0; off >>= 1) {
        sd += __shfl_xor(sd, off);
        qd += __shfl_xor(qd, off);
    }
    if (lane == 0) { sbuf[2 * wv] = sd; sbuf[2 * wv + 1] = qd; }
    __syncthreads();
    const double S = sbuf[0] + sbuf[2] + sbuf[4] + sbuf[6];
    const double Q = sbuf[1] + sbuf[3] + sbuf[5] + sbuf[7];
    const double mean = S / (double)NTOT;
    const double var  = Q / (double)NTOT - mean * mean;
    const double scl  = (double)gam / sqrt(var + 1e-5);
    scl_out = (float)scl;
    shf_out = (float)((double)bet - mean * scl);
}

// MFMA conv (Toeplitz): out[ct] += sum_ky A_ky(16x32) x B_ky(32x16)
//   A_ky[m][k] = tile[row0+m+ky][ct*16 + k]  (tile col t <-> gx = bx + t - 8)
//   B_ky[k][n] = w[ky][k-n-6] if 0 <= k-n-6 <= 4 else 0
// MODE 0: y (fp32) identity -> t1 bf16
// MODE 1: stats(P1) -> (s1,h1); t1 -> shrink(n1,l0) -> t2; statsOut=(s1,h1)
// MODE 2: stats(P2) -> (s2,h2); reads (s1,h1); t1,t2 -> shrink -> t3/out
// Grid: 1024 x 1-D; bijective XCD swizzle (1024 % 8 == 0).
template <int MODE, bool OBF>
__global__ __launch_bounds__(256, 4) void conv_k(
    const float* __restrict__ yin,
    const unsigned short* __restrict__ t1,
    const unsigned short* __restrict__ t2,
    unsigned short* __restrict__ outbf,
    float* __restrict__ outf32,
    const float* __restrict__ wgt,
    const float* __restrict__ bias,
    const float* __restrict__ prevPart,
    const float* __restrict__ statsIn,
    float* __restrict__ statsOut,
    const float* __restrict__ gamma,
    const float* __restrict__ beta,
    const float* __restrict__ lambd,
    float* __restrict__ partials)
{
    __shared__ unsigned short tile[TROWS * TPIT];   // 40,128 B
    __shared__ double sbuf[8];                      // stats scratch

    const int tid = threadIdx.x;
    const int lin = blockIdx.x;
    // XCD-bijective swizzle: XCD k owns tiles [k*128, (k+1)*128) = 8 images
    const int swz = ((lin & 7) << 7) | (lin >> 3);
    const int img = swz >> 4;
    const int rem = swz & 15;
    const int by = ((rem >> 2) & 3) * TS;
    const int bx = (rem & 3) * TS;
    const size_t ibase = (size_t)img * (HH * WW);

    const int lane = tid & 63;
    const int lm = lane & 15;
    const int kb = lane >> 4;
    const int wv = tid >> 6;

    // uniform weights -> SGPRs; lane-local B fragments
    float wloc[25];
#pragma unroll
    for (int i = 0; i < 25; i++) wloc[i] = wgt[i];
    const int basei = kb * 8 - lm - 6;
    short8 bfr[5];
#pragma unroll
    for (int ky = 0; ky < 5; ky++) {
        unsigned pkw[4];
#pragma unroll
        for (int jj = 0; jj < 4; jj++) {
            float v0 = 0.f, v1 = 0.f;
            const int i0 = basei + 2 * jj, i1 = i0 + 1;
#pragma unroll
            for (int t = 0; t < 5; t++) {
                if (i0 == t) v0 = wloc[ky * 5 + t];
                if (i1 == t) v1 = wloc[ky * 5 + t];
            }
            pkw[jj] = cvtpk(v0, v1);
        }
        union { unsigned u[4]; short8 s; } cv;
        cv.u[0]=pkw[0]; cv.u[1]=pkw[1]; cv.u[2]=pkw[2]; cv.u[3]=pkw[3];
        bfr[ky] = cv.s;
    }

    auto loadT = [&](int task, uint4& A, uint4& B) {
        A = make_uint4(0u,0u,0u,0u); B = make_uint4(0u,0u,0u,0u);
        const int row = task / TCH;
        const int ch  = task - row * TCH;
        const int gy  = by + row - 2;
        const int gx0 = bx + ch * 8 - 8;
        if (task < NTASK && gy >= 0 && gy < HH && gx0 >= 0 && gx0 <= WW - 8) {
            const size_t g = ibase + (size_t)gy * WW + gx0;
            if constexpr (MODE == 0) {
                A = *(const uint4*)(yin + g);
                B = *(const uint4*)(yin + g + 4);
            } else if constexpr (MODE == 1) {
                A = *(const uint4*)(t1 + g);
            } else {
                A = *(const uint4*)(t1 + g);
                B = *(const uint4*)(t2 + g);
            }
        }
    };

    // issue first 3 tasks' loads BEFORE stats (latency overlap)
    uint4 sA0, sB0, sA1, sB1, sA2, sB2;
    loadT(tid,        sA0, sB0);
    loadT(tid + 256,  sA1, sB1);
    loadT(tid + 512,  sA2, sB2);

    float s1 = 0.f, h1 = 0.f, s2v = 0.f, h2 = 0.f, lam = 0.f;
    if constexpr (MODE == 1) {
        stats_fast(prevPart, sbuf, tid, lane, wv, gamma[0], beta[0], s1, h1);
        lam = lambd[0];
        if (lin == 0 && tid == 0) { statsOut[0] = s1; statsOut[1] = h1; }
    }
    if constexpr (MODE == 2) {
        stats_fast(prevPart, sbuf, tid, lane, wv, gamma[0], beta[0], s2v, h2);
        s1 = statsIn[0]; h1 = statsIn[1];
        lam = lambd[1];
    }

    auto procT = [&](int task, uint4 A, uint4 B) {
        const int row = task / TCH;
        const int ch  = task - row * TCH;
        uint4 pk = make_uint4(0u,0u,0u,0u);
        if constexpr (MODE == 0) {
            const float4 a = *(const float4*)&A;
            const float4 b = *(const float4*)&B;
            pk.x = cvtpk(a.x, a.y); pk.y = cvtpk(a.z, a.w);
            pk.z = cvtpk(b.x, b.y); pk.w = cvtpk(b.z, b.w);
        } else if constexpr (MODE == 1) {
            float f1[8]; bf8(A, f1);
            float v[8];
#pragma unroll
            for (int k = 0; k < 8; k++)
                v[k] = shrinkf(__builtin_fmaf(f1[k], s1, h1), lam);
            pk.x = cvtpk(v[0], v[1]); pk.y = cvtpk(v[2], v[3]);
            pk.z = cvtpk(v[4], v[5]); pk.w = cvtpk(v[6], v[7]);
        } else {
            float f1[8], f2[8]; bf8(A, f1); bf8(B, f2);
            float v[8];
#pragma unroll
            for (int k = 0; k < 8; k++) {
                float x = __builtin_fmaf(f2[k], s2v, h2)
                        + __builtin_fmaf(f1[k], s1, h1);
                v[k] = shrinkf(x, lam);
            }
            pk.x = cvtpk(v[0], v[1]); pk.y = cvtpk(v[2], v[3]);
            pk.z = cvtpk(v[4], v[5]); pk.w = cvtpk(v[6], v[7]);
        }
        // OOB chunk: reference zero-pads the post-transform conv input
        const int gy  = by + row - 2;
        const int gx0 = bx + ch * 8 - 8;
        if (!(gy >= 0 && gy < HH && gx0 >= 0 && gx0 <= WW - 8))
            pk = make_uint4(0u,0u,0u,0u);
        *(uint4*)&tile[row * TPIT + ch * 8] = pk;
    };

#pragma unroll
    for (int t = 0; t < NITER; t++) {
        const int task = tid + t * 256;
        if (task < NTASK) procT(task, sA0, sB0);
        sA0 = sA1; sB0 = sB1;
        sA1 = sA2; sB1 = sB2;
        if (t + 3 < NITER) loadT(tid + (t + 3) * 256, sA2, sB2);
        else { sA2 = make_uint4(0u,0u,0u,0u); sB2 = make_uint4(0u,0u,0u,0u); }
    }

    const float b0 = bias[0];
    __syncthreads();

    // ---- MFMA phase: wave wv owns 32 output rows x 128 cols ----
    const int r0w = wv * 32;

    f32x4 acc[2][8];
#pragma unroll
    for (int st = 0; st < 2; st++)
#pragma unroll
        for (int ct = 0; ct < 8; ct++)
            acc[st][ct] = (f32x4){0.f, 0.f, 0.f, 0.f};

#pragma unroll
    for (int ky = 0; ky < 5; ky++) {
        const short8 b = bfr[ky];
#pragma unroll
        for (int st = 0; st < 2; st++) {
            const unsigned short* ab = &tile[(r0w + st * 16 + lm + ky) * TPIT + kb * 8];
#pragma unroll
            for (int ct = 0; ct < 8; ct++) {
                short8 a = *(const short8*)(ab + ct * 16);
                acc[st][ct] = __builtin_amdgcn_mfma_f32_16x16x32_bf16(a, b, acc[st][ct], 0, 0, 0);
            }
        }
    }

    // ---- epilogue: lane holds rows kb*4+e, col lm of each 16x16 tile ----
    float s = 0.f, q = 0.f;
#pragma unroll
    for (int st = 0; st < 2; st++) {
#pragma unroll
        for (int ct = 0; ct < 8; ct++) {
            const f32x4 a = acc[st][ct];
            const int grow0 = by + r0w + st * 16 + kb * 4;
            const size_t base = ibase + (size_t)grow0 * WW + bx + ct * 16 + lm;
            if constexpr (OBF) {
                unsigned p01 = cvtpk(a[0] + b0, a[1] + b0);
                unsigned p23 = cvtpk(a[2] + b0, a[3] + b0);
                outbf[base]          = (unsigned short)(p01 & 0xffffu);
                outbf[base + WW]     = (unsigned short)(p01 >> 16);
                outbf[base + 2 * WW] = (unsigned short)(p23 & 0xffffu);
                outbf[base + 3 * WW] = (unsigned short)(p23 >> 16);
                float fr0 = lo2f(p01), fr1 = hi2f(p01), fr2 = lo2f(p23), fr3 = hi2f(p23);
                s += fr0 + fr1 + fr2 + fr3;
                q = __builtin_fmaf(fr0, fr0, __builtin_fmaf(fr1, fr1,
                    __builtin_fmaf(fr2, fr2, __builtin_fmaf(fr3, fr3, q))));
            } else {
                float f0 = a[0] + b0, f1v = a[1] + b0, f2v = a[2] + b0, f3v = a[3] + b0;
                outf32[base]          = f0;
                outf32[base + WW]     = f1v;
                outf32[base + 2 * WW] = f2v;
                outf32[base + 3 * WW] = f3v;
                s += f0 + f1v + f2v + f3v;
                q = __builtin_fmaf(f0, f0, __builtin_fmaf(f1v, f1v,
                    __builtin_fmaf(f2v, f2v, __builtin_fmaf(f3v, f3v, q))));
            }
        }
    }

    // ---- tail: per-wave butterfly, NO barriers; one partial pair per wave ----
#pragma unroll
    for (int off = 32; off > 0; off >>= 1) {
        s += __shfl_xor(s, off);
        q += __shfl_xor(q, off);
    }
    if (lane == 0) {
        partials[(swz * 4 + wv) * 2]     = s;
        partials[(swz * 4 + wv) * 2 + 1] = q;
    }
}

// out = shrink(n3(t3) + n1(t1), lambd[2]); reduces P3 -> (s3,h3) in-kernel.
template <bool T3BF>
__global__ __launch_bounds__(256) void final_k(
    const unsigned short* __restrict__ t1,
    const unsigned short* __restrict__ t3b,
    float* __restrict__ io,
    const float* __restrict__ p3,
    const float* __restrict__ statsIn,
    const float* __restrict__ gamma,
    const float* __restrict__ beta,
    const float* __restrict__ lambd)
{
    __shared__ double sbuf[8];
    const int tid = threadIdx.x;
    const int lane = tid & 63;
    const int wv = tid >> 6;

    float s3, h3;
    stats_fast(p3, sbuf, tid, lane, wv, gamma[0], beta[0], s3, h3);
    const float s1 = statsIn[0], h1 = statsIn[1];
    const float lam = lambd[2];

#pragma unroll
    for (int c = 0; c < 8; c++) {
        const size_t idx = ((size_t)c * 1024 + blockIdx.x) * 256 + tid;
        const size_t base = idx * 8;

        uint4 u1 = *(const uint4*)(t1 + base);
        float f1[8]; bf8(u1, f1);

        float t3v[8];
        if constexpr (T3BF) {
            uint4 u3 = *(const uint4*)(t3b + base);
            bf8(u3, t3v);
        } else {
            float4 a0 = *(const float4*)(io + base);
            float4 a1 = *(const float4*)(io + base + 4);
            t3v[0]=a0.x; t3v[1]=a0.y; t3v[2]=a0.z; t3v[3]=a0.w;
            t3v[4]=a1.x; t3v[5]=a1.y; t3v[6]=a1.z; t3v[7]=a1.w;
        }

        float r[8];
#pragma unroll
        for (int k = 0; k < 8; k++) {
            float v = __builtin_fmaf(t3v[k], s3, h3) + __builtin_fmaf(f1[k], s1, h1);
            r[k] = shrinkf(v, lam);
        }
        *(float4*)(io + base)     = make_float4(r[0], r[1], r[2], r[3]);
        *(float4*)(io + base + 4) = make_float4(r[4], r[5], r[6], r[7]);
    }
}

extern "C" void kernel_launch(void* const* d_in, const int* in_sizes, int n_in,
                              void* d_out, int out_size, void* d_ws, size_t ws_size,
                              hipStream_t stream)
{
    const float* y     = (const float*)d_in[0];
    const float* wgt   = (const float*)d_in[1];
    const float* bias  = (const float*)d_in[2];
    const float* gamma = (const float*)d_in[3];
    const float* beta  = (const float*)d_in[4];
    const float* lambd = (const float*)d_in[5];
    float* out = (float*)d_out;

    char* ws = (char*)d_ws;
    unsigned short* t1 = (unsigned short*)ws;                    // 33,554,432 B
    unsigned short* t2 = (unsigned short*)(ws + 33554432ull);    // 33,554,432 B
    unsigned short* t3 = (unsigned short*)(ws + 67108864ull);    // 33,554,432 B
    const bool t3bf = (ws_size >= 100761608ull);
    const size_t poff = t3bf ? 100663296ull : 67108864ull;
    float* p1    = (float*)(ws + poff);                 // 32 KB (4096 pairs)
    float* p2    = (float*)(ws + poff + 32768ull);      // 32 KB
    float* p3    = (float*)(ws + poff + 65536ull);      // 32 KB
    float* stats = (float*)(ws + poff + 98304ull);      // 8 B

    dim3 grid(1024, 1, 1), blk(256, 1, 1);
    conv_k<0, true><<<grid, blk, 0, stream>>>(y, nullptr, nullptr, t1, nullptr,
                                              wgt, bias, nullptr, nullptr, nullptr,
                                              gamma, beta, lambd, p1);
    conv_k<1, true><<<grid, blk, 0, stream>>>(nullptr, t1, nullptr, t2, nullptr,
                                              wgt, bias, p1, nullptr, stats,
                                              gamma, beta, lambd, p2);
    if (t3bf) {
        conv_k<2, true><<<grid, blk, 0, stream>>>(nullptr, t1, t2, t3, nullptr,
                                                  wgt, bias, p2, stats, nullptr,
                                                  gamma, beta, lambd, p3);
        final_k<true><<<grid, blk, 0, stream>>>(t1, t3, out, p3, stats,
                                                gamma, beta, lambd);
    } else {
        conv_k<2, false><<<grid, blk, 0, stream>>>(nullptr, t1, t2, nullptr, out,
                                                   wgt, bias, p2, stats, nullptr,
                                                   gamma, beta, lambd, p3);
        final_k<false><<<grid, blk, 0, stream>>>(t1, nullptr, out, p3, stats,
                                                 gamma, beta, lambd);
    }
}